// Round 2
// baseline (468.723 us; speedup 1.0000x reference)
//
#include <hip/hip_runtime.h>

typedef _Float16 f16;
typedef f16 f16x4 __attribute__((ext_vector_type(4)));
typedef f16 f16x8 __attribute__((ext_vector_type(8)));
typedef float f32x4 __attribute__((ext_vector_type(4)));

#define T_STEPS 512
#define INPUT   12
#define HID     20
#define KDIM    32           // 12 + 20 == MFMA K exactly
#define BSTRIDE 40           // padded row stride (f16) -> conflict-free b128 reads
#define BATCH   16           // batches per wave (MFMA N)
#define NTILES  5            // 5 x 16 gate-rows = 80 = 4*H

// intra-wave LDS RAW fence: no barrier needed (single wave per block)
static __device__ __forceinline__ void lds_fence() {
    asm volatile("s_waitcnt lgkmcnt(0)" ::: "memory");
}

__global__ __launch_bounds__(64) void lstm_kernel(
    const float* __restrict__ x,      // [8192,512,12]
    const float* __restrict__ w_ih,   // [80,12]
    const float* __restrict__ w_hh,   // [80,20]
    const float* __restrict__ b_ih,   // [80]
    const float* __restrict__ b_hh,   // [80]
    const float* __restrict__ w_out,  // [10,20]
    const float* __restrict__ b_out,  // [10]
    float* __restrict__ out)          // [8192,10]
{
    // Row-permuted combined weights, pre-scaled by -log2(e) (sigmoid gates) or
    // +2*log2(e) (g gate) so activations need no per-element scaling muls.
    // Tile w row r: gate (r&3) of unit 4w+(r>>2) -> lane (quad,col) acc regs
    // 0..3 = i,f,g,o of unit 4w+quad for batch col.
    __shared__ __align__(16) f16 Wc[80][KDIM];                 // 5 KB
    __shared__ __align__(16) f16 Bbuf[2][BATCH][BSTRIDE];      // 2.5 KB, [x(12)|h(20)|pad]

    const int lane = threadIdx.x;
    const int b    = lane & 15;        // MFMA N index = batch (also A-operand m index)
    const int quad = lane >> 4;

    // ---- build permuted, pre-scaled weight matrix (once, 40 iters) ----
    for (int i = lane; i < 80 * KDIM; i += 64) {
        int n = i >> 5, k = i & 31;
        int g = n & 3;                       // gate (i,f,g,o)
        int u = 4 * (n >> 4) + ((n >> 2) & 3);
        int row = g * HID + u;               // original row of [w_ih | w_hh]
        float v = (k < INPUT) ? w_ih[row * INPUT + k] : w_hh[row * HID + (k - INPUT)];
        float sc = (g == 2) ? 2.8853900817779268f : -1.4426950408889634f;
        Wc[n][k] = (f16)(v * sc);
    }

    // ---- scaled combined bias as MFMA C operand, unit u = 4w+quad ----
    f32x4 cbias[NTILES];
#pragma unroll
    for (int w = 0; w < NTILES; ++w) {
        int u = 4 * w + quad;
#pragma unroll
        for (int g = 0; g < 4; ++g) {
            float sc = (g == 2) ? 2.8853900817779268f : -1.4426950408889634f;
            cbias[w][g] = sc * (b_ih[g * HID + u] + b_hh[g * HID + u]);
        }
    }

    // zero h(-1) region of buf 0 (all 64 lanes x 5 units = 320 entries)
#pragma unroll
    for (int w = 0; w < NTILES; ++w)
        Bbuf[0][b][INPUT + 4 * w + quad] = (f16)0.f;

    // ---- x loaders: quads 0..2, lane (q,b) owns x[b][t][4q..4q+3] ----
    const bool xload = quad < 3;
    const float* xptr = x + (size_t)(blockIdx.x * BATCH + b) * (T_STEPS * INPUT) + 4 * quad;

    f32x4 q0 = {0.f,0.f,0.f,0.f}, q1 = q0, q2 = q0, q3 = q0;
    if (xload) {
        f32x4 x0 = *(const f32x4*)xptr;          // x(0)
        f16x4 xc;
#pragma unroll
        for (int j = 0; j < 4; ++j) xc[j] = (f16)x0[j];
        *(f16x4*)&Bbuf[0][b][4 * quad] = xc;     // stage x(0)
        q0 = *(const f32x4*)(xptr + 1 * INPUT);  // x(1)
        q1 = *(const f32x4*)(xptr + 2 * INPUT);  // x(2)
        q2 = *(const f32x4*)(xptr + 3 * INPUT);  // x(3)
        q3 = *(const f32x4*)(xptr + 4 * INPUT);  // x(4)
    }

    lds_fence();                                 // Wc + x(0) + h(-1) visible (same wave)

    // ---- stationary A fragments: A[m=lane&15][k=quad*8+j] for each tile ----
    f16x8 afrag[NTILES];
#pragma unroll
    for (int w = 0; w < NTILES; ++w)
        afrag[w] = *(const f16x8*)&Wc[16 * w + b][quad * 8];

    float cc[NTILES] = {0.f, 0.f, 0.f, 0.f, 0.f};

    // one recurrence step; pj = buffer parity (compile-time after inlining)
    auto step = [&](int pj, f32x4& qreg, int tload) {
        lds_fence();                             // h(t-1)/x(t) writes complete
        f16x8 bfrag = *(const f16x8*)&Bbuf[pj][b][quad * 8];

        // stage x(t+1) into next buffer; reload queue slot with x(t+5)
        if (xload) {
            f16x4 xc;
#pragma unroll
            for (int j = 0; j < 4; ++j) xc[j] = (f16)qreg[j];
            *(f16x4*)&Bbuf[pj ^ 1][b][4 * quad] = xc;
            int tl = tload < T_STEPS ? tload : T_STEPS - 1;
            qreg = *(const f32x4*)(xptr + (size_t)tl * INPUT);
        }

        // all 5 gate tiles: independent MFMAs, same B fragment
        f32x4 acc[NTILES];
#pragma unroll
        for (int w = 0; w < NTILES; ++w)
            acc[w] = __builtin_amdgcn_mfma_f32_16x16x32_f16(afrag[w], bfrag, cbias[w], 0, 0, 0);

        // fused activations, 7 transcendentals/unit:
        //   ei=2^(-1.44a_i) etc, eg=2^(2.89a_g); A*=1+e*
        //   c  = (c*Ai*Ag + (eg-1)*Af) / (Ai*Af*Ag)      [1 rcp]
        //   h  = (et-1)/(At*Ao), et=2^(2.89c)            [1 rcp]
#pragma unroll
        for (int w = 0; w < NTILES; ++w) {
            float ei = __builtin_amdgcn_exp2f(acc[w][0]);
            float ef = __builtin_amdgcn_exp2f(acc[w][1]);
            float eg = __builtin_amdgcn_exp2f(acc[w][2]);
            float eo = __builtin_amdgcn_exp2f(acc[w][3]);
            float Ai = 1.f + ei, Af = 1.f + ef, Ag = 1.f + eg, Ao = 1.f + eo;
            float P  = Ai * Ag;
            float rD = __builtin_amdgcn_rcpf(P * Af);
            float nm = __builtin_fmaf(eg - 1.f, Af, cc[w] * P);
            float c  = nm * rD;
            cc[w] = c;
            float et = __builtin_amdgcn_exp2f(2.8853900817779268f * c);
            float At = 1.f + et;
            float rM = __builtin_amdgcn_rcpf(At * Ao);
            float h  = (et - 1.f) * rM;
            Bbuf[pj ^ 1][b][INPUT + 4 * w + quad] = (f16)h;   // publish h(t)
        }
    };

#pragma unroll 1
    for (int t4 = 0; t4 < T_STEPS; t4 += 4) {
        step(0, q0, t4 + 5);
        step(1, q1, t4 + 6);
        step(0, q2, t4 + 7);
        step(1, q3, t4 + 8);
    }

    lds_fence();                                 // h(T-1) writes (into buf 0) complete

    // ---- output projection: 160 outputs over 64 lanes ----
    for (int i = lane; i < BATCH * 10; i += 64) {
        int ob = i / 10, oo = i - 10 * ob;
        float s = b_out[oo];
#pragma unroll
        for (int u2 = 0; u2 < HID; ++u2)
            s += w_out[oo * HID + u2] * (float)Bbuf[0][ob][INPUT + u2];
        out[(size_t)(blockIdx.x * BATCH + ob) * 10 + oo] = s;
    }
}

extern "C" void kernel_launch(void* const* d_in, const int* in_sizes, int n_in,
                              void* d_out, int out_size, void* d_ws, size_t ws_size,
                              hipStream_t stream) {
    const float* x     = (const float*)d_in[0];
    const float* w_ih  = (const float*)d_in[1];
    const float* w_hh  = (const float*)d_in[2];
    const float* b_ih  = (const float*)d_in[3];
    const float* b_hh  = (const float*)d_in[4];
    const float* w_out = (const float*)d_in[5];
    const float* b_out = (const float*)d_in[6];
    float* out = (float*)d_out;

    const int blocks = 8192 / BATCH;   // 512 independent single-wave blocks, 2/CU
    hipLaunchKernelGGL(lstm_kernel, dim3(blocks), dim3(64), 0, stream,
                       x, w_ih, w_hh, b_ih, b_hh, w_out, b_out, out);
}